// Round 1
// 996.516 us; speedup vs baseline: 1.0346x; 1.0346x over previous
//
#include <hip/hip_runtime.h>

typedef unsigned short u16;
typedef unsigned int u32;
typedef __attribute__((ext_vector_type(8))) __bf16 bf16x8;
typedef __attribute__((ext_vector_type(4))) float f32x4;

// ---------- helpers ----------
__device__ __forceinline__ void gl_lds16(const void* g, void* l) {
  // async global->LDS, 16B per lane; LDS dest = wave-uniform base + lane*16
  __builtin_amdgcn_global_load_lds((__attribute__((address_space(1))) void*)g,
                                   (__attribute__((address_space(3))) void*)l,
                                   16, 0, 0);
}

__device__ __forceinline__ u16 f2bf(float f) {
  // RNE float->bf16 (inputs are finite; NaN not handled)
  u32 x = __builtin_bit_cast(u32, f);
  return (u16)((x + 0x7fffu + ((x >> 16) & 1u)) >> 16);
}

// ---------- fused fp32 -> bf16 convert for all 7 tensors (1 launch) ----------
// blocks 0..12287: inputs (3 x 4096 blocks), 12288..20479: weights (4 x 2048)
__global__ __launch_bounds__(256) void cvt_all(
    const float* __restrict__ q, const float* __restrict__ k, const float* __restrict__ v,
    const float* __restrict__ wq, const float* __restrict__ wk, const float* __restrict__ wv,
    const float* __restrict__ wo,
    u16* __restrict__ xq, u16* __restrict__ xk, u16* __restrict__ xv,
    u16* __restrict__ owq, u16* __restrict__ owk, u16* __restrict__ owv,
    u16* __restrict__ owo) {
  int bid = blockIdx.x;
  const float* src;
  u16* dst;
  int chunk;
  if (bid < 12288) {
    int t = bid >> 12;
    chunk = bid & 4095;
    src = (t == 0) ? q : (t == 1) ? k : v;
    dst = (t == 0) ? xq : (t == 1) ? xk : xv;
  } else {
    int b2 = bid - 12288;
    int t = b2 >> 11;
    chunk = b2 & 2047;
    src = (t == 0) ? wq : (t == 1) ? wk : (t == 2) ? wv : wo;
    dst = (t == 0) ? owq : (t == 1) ? owk : (t == 2) ? owv : owo;
  }
  int i = (chunk * 256 + (int)threadIdx.x) * 8;
  const float4* p = (const float4*)(src + i);
  float4 a = p[0], b = p[1];
  uint4 u;
  u.x = f2bf(a.x) | ((u32)f2bf(a.y) << 16);
  u.y = f2bf(a.z) | ((u32)f2bf(a.w) << 16);
  u.z = f2bf(b.x) | ((u32)f2bf(b.y) << 16);
  u.w = f2bf(b.z) | ((u32)f2bf(b.w) << 16);
  *(uint4*)(dst + i) = u;
}

// ---------- C = A * B^T  (A:[M,K] bf16, B:[N,K] bf16, C fp32 or bf16) ----------
// 128x128 tile, BK=32, 4 waves (2x2 of 64x64), XOR-swizzled LDS (chunk ^ ((row>>1)&3))
template <bool F32OUT>
__device__ __forceinline__ void gemm_body(const u16* __restrict__ A, const u16* __restrict__ B,
                                          void* __restrict__ Cptr, int m0, int n0, int N, int K,
                                          u16* As, u16* Bs) {
  const int tid = threadIdx.x;
  const int lane = tid & 63, w = tid >> 6;
  const int wm = (w & 1) * 64, wn = (w >> 1) * 64;
  const int fm = lane & 15, quad = lane >> 4;
  const int sr = lane >> 2, sc = lane & 3;  // staging: row within 16-row issue, chunk pos
  f32x4 acc[4][4] = {};
  for (int k0 = 0; k0 < K; k0 += 32) {
    __syncthreads();
    for (int i = w; i < 8; i += 4) {
      int r = i * 16 + sr;
      int ca = sc ^ ((r >> 1) & 3);  // swizzle: position sc holds chunk ca
      gl_lds16(A + (size_t)(m0 + r) * K + k0 + ca * 8, &As[i * 512]);
      gl_lds16(B + (size_t)(n0 + r) * K + k0 + ca * 8, &Bs[i * 512]);
    }
    __syncthreads();
    bf16x8 af[4], bfr[4];
#pragma unroll
    for (int t = 0; t < 4; t++) {
      int ra = wm + t * 16 + fm;
      af[t] = *(const bf16x8*)&As[ra * 32 + ((quad ^ ((ra >> 1) & 3)) << 3)];
      int rb = wn + t * 16 + fm;
      bfr[t] = *(const bf16x8*)&Bs[rb * 32 + ((quad ^ ((rb >> 1) & 3)) << 3)];
    }
#pragma unroll
    for (int mt = 0; mt < 4; mt++)
#pragma unroll
      for (int nt = 0; nt < 4; nt++)
        acc[mt][nt] = __builtin_amdgcn_mfma_f32_16x16x32_bf16(af[mt], bfr[nt], acc[mt][nt], 0, 0, 0);
  }
  const int er = quad * 4;
#pragma unroll
  for (int mt = 0; mt < 4; mt++)
#pragma unroll
    for (int nt = 0; nt < 4; nt++)
#pragma unroll
      for (int r = 0; r < 4; r++) {
        size_t idx = (size_t)(m0 + wm + mt * 16 + er + r) * N + (n0 + wn + nt * 16 + fm);
        if (F32OUT) ((float*)Cptr)[idx] = acc[mt][nt][r];
        else        ((u16*)Cptr)[idx] = f2bf(acc[mt][nt][r]);
      }
}

// Batched Q/K/V projection in one launch. blockIdx.y selects the GEMM:
//  y=0: Qb = Xq*Wq^T [4096x2048], y=1: Kb = Xk*Wk^T [4096x2048]
//  y=2: Vt = Wv*Xv^T [2048x4096]  (= V^T directly; transpose kernel eliminated)
__global__ __launch_bounds__(256, 2)
void gemm_qkv(const u16* __restrict__ Xq, const u16* __restrict__ Wqb, u16* __restrict__ Qb,
              const u16* __restrict__ Xk, const u16* __restrict__ Wkb, u16* __restrict__ Kb,
              const u16* __restrict__ Xv, const u16* __restrict__ Wvb, u16* __restrict__ Vt) {
  __shared__ u16 As[128 * 32];
  __shared__ u16 Bs[128 * 32];
  const int bid = blockIdx.x, z = blockIdx.y;
  const u16 *A, *B;
  u16* C;
  int N, m0, n0;
  if (z == 0) {
    A = Xq; B = Wqb; C = Qb; N = 2048;
    m0 = (bid >> 4) << 7; n0 = (bid & 15) << 7;
  } else if (z == 1) {
    A = Xk; B = Wkb; C = Kb; N = 2048;
    m0 = (bid >> 4) << 7; n0 = (bid & 15) << 7;
  } else {
    A = Wvb; B = Xv; C = Vt; N = 4096;
    m0 = (bid >> 5) << 7; n0 = (bid & 31) << 7;
  }
  gemm_body<false>(A, B, C, m0, n0, N, 2048, As, Bs);
}

// Output projection: out = ctx * Wo^T, fp32 out
__global__ __launch_bounds__(256, 2)
void gemm_out(const u16* __restrict__ A, const u16* __restrict__ B, float* __restrict__ C) {
  __shared__ u16 As[128 * 32];
  __shared__ u16 Bs[128 * 32];
  gemm_body<true>(A, B, C, (int)(blockIdx.y << 7), (int)(blockIdx.x << 7), 2048, 2048, As, Bs);
}

// ---------- attention: per-64-key-block softmax, block outputs summed ----------
// grid (qt=16, h=16, b=2), 256 threads; wave w owns q-rows [w*32, w*32+32)
// v2: double-buffered K/V staging (prefetch kb+1 during compute of kb),
//     single vmcnt(0)+s_barrier per iter, setprio around MFMA, exp2-folded softmax.
// Vt layout: [d 2048][b*2048+s] (row stride 4096), produced by gemm_qkv z=2.
__global__ __launch_bounds__(256, 2)
void attn_kernel(const u16* __restrict__ Q, const u16* __restrict__ Kmat,
                 const u16* __restrict__ Vt, float* __restrict__ attn_out,
                 u16* __restrict__ ctx) {
  __shared__ u16 Ks[2][64 * 128];   // [key][hd], 16B-chunk pos = c ^ (key&15)
  __shared__ u16 Vts[2][128 * 64];  // [dd][key], chunk pos = c ^ (dd&7)
  __shared__ u16 Ps[128 * 64];      // [qrow][key], chunk pos = c ^ (row&7); wave-private rows
  const int tid = threadIdx.x, lane = tid & 63, w = tid >> 6;
  const int qt = blockIdx.x, h = blockIdx.y, b = blockIdx.z;
  const int q0 = qt * 128;
  const int fm = lane & 15, quad = lane >> 4;
  // (1/sqrt(128)) * log2(e): softmax exp((v-mx)/scale) == exp2((v-mx)*c)
  const float c_e2 = 0.088388347648318447f * 1.4426950408889634f;

  // Q fragments in registers (one-time scattered 16B global reads)
  bf16x8 qf[2][4];
  {
    const u16* Qg = Q + (size_t)(b * 2048 + q0 + w * 32 + fm) * 2048 + h * 128;
#pragma unroll
    for (int mt = 0; mt < 2; mt++)
#pragma unroll
      for (int kt = 0; kt < 4; kt++)
        qf[mt][kt] = *(const bf16x8*)(Qg + (size_t)mt * 16 * 2048 + kt * 32 + quad * 8);
  }
  f32x4 cacc[2][8] = {};  // ctx accumulator, persists across all 32 k-blocks
  const u16* Kg = Kmat + (size_t)b * 2048 * 2048 + h * 128;
  const u16* Vg = Vt + (size_t)(h * 128) * 4096 + b * 2048;
  const int krl = lane >> 4, kcl = lane & 15;  // K staging: 4 rows x 16 chunks / issue
  const int vrl = lane >> 3, vcl = lane & 7;   // V staging: 8 rows x 8 chunks / issue

#define STAGE(buf, kbb)                                                              \
  for (int i = w; i < 16; i += 4) {                                                  \
    int rk = i * 4 + krl;                                                            \
    int ck = kcl ^ (rk & 15);                                                        \
    gl_lds16(Kg + (size_t)((kbb) * 64 + rk) * 2048 + ck * 8, &Ks[(buf)][i * 512]);   \
    int rv = i * 8 + vrl;                                                            \
    int cv = vcl ^ (rv & 7);                                                         \
    gl_lds16(Vg + (size_t)rv * 4096 + (kbb) * 64 + cv * 8, &Vts[(buf)][i * 512]);    \
  }

  // prologue: stage k-block 0 into buffer 0
  STAGE(0, 0)
  asm volatile("s_waitcnt vmcnt(0)" ::: "memory");
  __builtin_amdgcn_s_barrier();

  for (int kb = 0; kb < 32; kb++) {
    const int cur = kb & 1;
    // issue next tile's async loads first; latency hides under compute below
    if (kb < 31) { STAGE(cur ^ 1, kb + 1) }

    // S = Q K^T  (this wave: 32 q-rows x 64 keys)
    f32x4 sacc[2][4] = {};
#pragma unroll
    for (int kt = 0; kt < 4; kt++) {
      bf16x8 kf[4];
#pragma unroll
      for (int nt = 0; nt < 4; nt++) {
        int rk = nt * 16 + fm;
        int ck = (kt * 4 + quad) ^ (rk & 15);
        kf[nt] = *(const bf16x8*)&Ks[cur][rk * 128 + ck * 8];
      }
      __builtin_amdgcn_s_setprio(1);
#pragma unroll
      for (int mt = 0; mt < 2; mt++)
#pragma unroll
        for (int nt = 0; nt < 4; nt++)
          sacc[mt][nt] = __builtin_amdgcn_mfma_f32_16x16x32_bf16(qf[mt][kt], kf[nt], sacc[mt][nt], 0, 0, 0);
      __builtin_amdgcn_s_setprio(0);
    }

    // per-row softmax over this 64-key block; write fp32 probs + bf16 P tile
#pragma unroll
    for (int mt = 0; mt < 2; mt++)
#pragma unroll
      for (int r = 0; r < 4; r++) {
        float v0 = sacc[mt][0][r], v1 = sacc[mt][1][r], v2 = sacc[mt][2][r], v3 = sacc[mt][3][r];
        float mx = fmaxf(fmaxf(v0, v1), fmaxf(v2, v3));
        mx = fmaxf(mx, __shfl_xor(mx, 1));
        mx = fmaxf(mx, __shfl_xor(mx, 2));
        mx = fmaxf(mx, __shfl_xor(mx, 4));
        mx = fmaxf(mx, __shfl_xor(mx, 8));
        float e0 = exp2f((v0 - mx) * c_e2);
        float e1 = exp2f((v1 - mx) * c_e2);
        float e2 = exp2f((v2 - mx) * c_e2);
        float e3 = exp2f((v3 - mx) * c_e2);
        float s = e0 + e1 + e2 + e3;
        s += __shfl_xor(s, 1);
        s += __shfl_xor(s, 2);
        s += __shfl_xor(s, 4);
        s += __shfl_xor(s, 8);
        float inv = __builtin_amdgcn_rcpf(s);  // s in [1,64]; ~1ulp, well within tol
        float p0 = e0 * inv, p1 = e1 * inv, p2 = e2 * inv, p3 = e3 * inv;
        int row = w * 32 + mt * 16 + quad * 4 + r;
        size_t ob = ((size_t)((b * 16 + h) * 2048 + q0 + row)) * 2048 + kb * 64;
        attn_out[ob + fm] = p0;
        attn_out[ob + 16 + fm] = p1;
        attn_out[ob + 32 + fm] = p2;
        attn_out[ob + 48 + fm] = p3;
        int rw7 = row & 7, fh = fm >> 3, fl = fm & 7;
        u16* pp = &Ps[row * 64];
        pp[(((0 + fh) ^ rw7) << 3) + fl] = f2bf(p0);
        pp[(((2 + fh) ^ rw7) << 3) + fl] = f2bf(p1);
        pp[(((4 + fh) ^ rw7) << 3) + fl] = f2bf(p2);
        pp[(((6 + fh) ^ rw7) << 3) + fl] = f2bf(p3);
      }

    // ctx += P * V   (Ps rows are wave-private: no barrier needed)
#pragma unroll
    for (int kt = 0; kt < 2; kt++) {
      bf16x8 pa[2], vb[8];
#pragma unroll
      for (int mt = 0; mt < 2; mt++) {
        int rp = w * 32 + mt * 16 + fm;
        int cp = (kt * 4 + quad) ^ (rp & 7);
        pa[mt] = *(const bf16x8*)&Ps[rp * 64 + cp * 8];
      }
#pragma unroll
      for (int nt = 0; nt < 8; nt++) {
        int rv = nt * 16 + fm;
        int cv = (kt * 4 + quad) ^ (rv & 7);
        vb[nt] = *(const bf16x8*)&Vts[cur][rv * 64 + cv * 8];
      }
      __builtin_amdgcn_s_setprio(1);
#pragma unroll
      for (int mt = 0; mt < 2; mt++)
#pragma unroll
        for (int nt = 0; nt < 8; nt++)
          cacc[mt][nt] = __builtin_amdgcn_mfma_f32_16x16x32_bf16(pa[mt], vb[nt], cacc[mt][nt], 0, 0, 0);
      __builtin_amdgcn_s_setprio(0);
    }

    // prefetch (issued at top of iter) has had the whole compute phase to land
    if (kb < 31) {
      asm volatile("s_waitcnt vmcnt(0)" ::: "memory");
      __builtin_amdgcn_s_barrier();
    }
  }
#undef STAGE

  // ctx [B,S,D] layout (= transpose(0,2,1,3).reshape fused)
#pragma unroll
  for (int mt = 0; mt < 2; mt++)
#pragma unroll
    for (int nt = 0; nt < 8; nt++)
#pragma unroll
      for (int r = 0; r < 4; r++) {
        int row = q0 + w * 32 + mt * 16 + quad * 4 + r;
        int col = h * 128 + nt * 16 + fm;
        ctx[(size_t)(b * 2048 + row) * 2048 + col] = f2bf(cacc[mt][nt][r]);
      }
}

extern "C" void kernel_launch(void* const* d_in, const int* in_sizes, int n_in,
                              void* d_out, int out_size, void* d_ws, size_t ws_size,
                              hipStream_t stream) {
  const float* query = (const float*)d_in[0];
  const float* key   = (const float*)d_in[1];
  const float* value = (const float*)d_in[2];
  const float* Wq = (const float*)d_in[3];
  const float* Wk = (const float*)d_in[4];
  const float* Wv = (const float*)d_in[5];
  const float* Wo = (const float*)d_in[6];
  // d_in[7] = block_size (fixed 64)

  float* out  = (float*)d_out;
  float* attn = out + (size_t)8388608;  // [B,H,S,S] region

  // workspace (bf16, 96 MiB)
  u16* ws  = (u16*)d_ws;
  u16* wqb = ws;
  u16* wkb = wqb + 4194304;
  u16* wvb = wkb + 4194304;
  u16* wob = wvb + 4194304;
  u16* Qb  = wob + 4194304;
  u16* Kb  = Qb + 8388608;
  u16* Vtb = Kb + 8388608;   // [d 2048][b*s 4096] = V^T, written directly by gemm_qkv
  u16* ctx = Vtb + 8388608;
  // bf16 input copies live in the attn-weights region (dead before attn writes it)
  u16* Xq = (u16*)attn;
  u16* Xk = Xq + 8388608;
  u16* Xv = Xk + 8388608;

  cvt_all<<<20480, 256, 0, stream>>>(query, key, value, Wq, Wk, Wv, Wo,
                                     Xq, Xk, Xv, wqb, wkb, wvb, wob);

  gemm_qkv<<<dim3(512, 3, 1), 256, 0, stream>>>(Xq, wqb, Qb, Xk, wkb, Kb, Xv, wvb, Vtb);

  attn_kernel<<<dim3(16, 16, 2), 256, 0, stream>>>(Qb, Kb, Vtb, attn, ctx);

  gemm_out<<<dim3(16, 32, 1), 256, 0, stream>>>(ctx, wob, out);
}

// Round 2
// 980.810 us; speedup vs baseline: 1.0512x; 1.0160x over previous
//
#include <hip/hip_runtime.h>

typedef unsigned short u16;
typedef unsigned int u32;
typedef __attribute__((ext_vector_type(8))) __bf16 bf16x8;
typedef __attribute__((ext_vector_type(4))) float f32x4;

// ---------- helpers ----------
__device__ __forceinline__ void gl_lds16(const void* g, void* l) {
  // async global->LDS, 16B per lane; LDS dest = wave-uniform base + lane*16
  __builtin_amdgcn_global_load_lds((__attribute__((address_space(1))) void*)g,
                                   (__attribute__((address_space(3))) void*)l,
                                   16, 0, 0);
}

__device__ __forceinline__ u16 f2bf(float f) {
  // RNE float->bf16 (inputs are finite; NaN not handled)
  u32 x = __builtin_bit_cast(u32, f);
  return (u16)((x + 0x7fffu + ((x >> 16) & 1u)) >> 16);
}

// ---------- fused fp32 -> bf16 convert for all 7 tensors (1 launch) ----------
__global__ __launch_bounds__(256) void cvt_all(
    const float* __restrict__ q, const float* __restrict__ k, const float* __restrict__ v,
    const float* __restrict__ wq, const float* __restrict__ wk, const float* __restrict__ wv,
    const float* __restrict__ wo,
    u16* __restrict__ xq, u16* __restrict__ xk, u16* __restrict__ xv,
    u16* __restrict__ owq, u16* __restrict__ owk, u16* __restrict__ owv,
    u16* __restrict__ owo) {
  int bid = blockIdx.x;
  const float* src;
  u16* dst;
  int chunk;
  if (bid < 12288) {
    int t = bid >> 12;
    chunk = bid & 4095;
    src = (t == 0) ? q : (t == 1) ? k : v;
    dst = (t == 0) ? xq : (t == 1) ? xk : xv;
  } else {
    int b2 = bid - 12288;
    int t = b2 >> 11;
    chunk = b2 & 2047;
    src = (t == 0) ? wq : (t == 1) ? wk : (t == 2) ? wv : wo;
    dst = (t == 0) ? owq : (t == 1) ? owk : (t == 2) ? owv : owo;
  }
  int i = (chunk * 256 + (int)threadIdx.x) * 8;
  const float4* p = (const float4*)(src + i);
  float4 a = p[0], b = p[1];
  uint4 u;
  u.x = f2bf(a.x) | ((u32)f2bf(a.y) << 16);
  u.y = f2bf(a.z) | ((u32)f2bf(a.w) << 16);
  u.z = f2bf(b.x) | ((u32)f2bf(b.y) << 16);
  u.w = f2bf(b.z) | ((u32)f2bf(b.w) << 16);
  *(uint4*)(dst + i) = u;
}

// ---------- C = A * B^T  (A:[M,K] bf16, B:[N,K] bf16, C fp32 or bf16) ----------
// 128x128 tile, BK=32, 4 waves (2x2 of 64x64), XOR-swizzled LDS (chunk ^ ((row>>1)&3))
template <bool F32OUT>
__device__ __forceinline__ void gemm_body(const u16* __restrict__ A, const u16* __restrict__ B,
                                          void* __restrict__ Cptr, int m0, int n0, int N, int K,
                                          u16* As, u16* Bs) {
  const int tid = threadIdx.x;
  const int lane = tid & 63, w = tid >> 6;
  const int wm = (w & 1) * 64, wn = (w >> 1) * 64;
  const int fm = lane & 15, quad = lane >> 4;
  const int sr = lane >> 2, sc = lane & 3;  // staging: row within 16-row issue, chunk pos
  f32x4 acc[4][4] = {};
  for (int k0 = 0; k0 < K; k0 += 32) {
    __syncthreads();
    for (int i = w; i < 8; i += 4) {
      int r = i * 16 + sr;
      int ca = sc ^ ((r >> 1) & 3);  // swizzle: position sc holds chunk ca
      gl_lds16(A + (size_t)(m0 + r) * K + k0 + ca * 8, &As[i * 512]);
      gl_lds16(B + (size_t)(n0 + r) * K + k0 + ca * 8, &Bs[i * 512]);
    }
    __syncthreads();
    bf16x8 af[4], bfr[4];
#pragma unroll
    for (int t = 0; t < 4; t++) {
      int ra = wm + t * 16 + fm;
      af[t] = *(const bf16x8*)&As[ra * 32 + ((quad ^ ((ra >> 1) & 3)) << 3)];
      int rb = wn + t * 16 + fm;
      bfr[t] = *(const bf16x8*)&Bs[rb * 32 + ((quad ^ ((rb >> 1) & 3)) << 3)];
    }
#pragma unroll
    for (int mt = 0; mt < 4; mt++)
#pragma unroll
      for (int nt = 0; nt < 4; nt++)
        acc[mt][nt] = __builtin_amdgcn_mfma_f32_16x16x32_bf16(af[mt], bfr[nt], acc[mt][nt], 0, 0, 0);
  }
  const int er = quad * 4;
#pragma unroll
  for (int mt = 0; mt < 4; mt++)
#pragma unroll
    for (int nt = 0; nt < 4; nt++)
#pragma unroll
      for (int r = 0; r < 4; r++) {
        size_t idx = (size_t)(m0 + wm + mt * 16 + er + r) * N + (n0 + wn + nt * 16 + fm);
        if (F32OUT) ((float*)Cptr)[idx] = acc[mt][nt][r];
        else        ((u16*)Cptr)[idx] = f2bf(acc[mt][nt][r]);
      }
}

// Batched Q/K/V projection in one launch, XCD-chunked block swizzle (T1).
//  work z=0: Qb = Xq*Wq^T [4096x2048], z=1: Kb = Xk*Wk^T [4096x2048]
//  work z=2: Vt = Wv*Xv^T [2048x4096]  (= V^T directly)
__global__ __launch_bounds__(256, 2)
void gemm_qkv(const u16* __restrict__ Xq, const u16* __restrict__ Wqb, u16* __restrict__ Qb,
              const u16* __restrict__ Xk, const u16* __restrict__ Wkb, u16* __restrict__ Kb,
              const u16* __restrict__ Xv, const u16* __restrict__ Wvb, u16* __restrict__ Vt) {
  __shared__ u16 As[128 * 32];
  __shared__ u16 Bs[128 * 32];
  // T1: nwg=1536 (%8==0); XCD x executes works [x*192, x*192+192) -> A-row panels stay L2-hot
  const int flat = blockIdx.x + (blockIdx.y << 9);
  const int work = (flat & 7) * 192 + (flat >> 3);
  const int z = work >> 9, bid = work & 511;
  const u16 *A, *B;
  u16* C;
  int N, m0, n0;
  if (z == 0) {
    A = Xq; B = Wqb; C = Qb; N = 2048;
    m0 = (bid >> 4) << 7; n0 = (bid & 15) << 7;
  } else if (z == 1) {
    A = Xk; B = Wkb; C = Kb; N = 2048;
    m0 = (bid >> 4) << 7; n0 = (bid & 15) << 7;
  } else {
    A = Wvb; B = Xv; C = Vt; N = 4096;
    m0 = (bid >> 5) << 7; n0 = (bid & 31) << 7;
  }
  gemm_body<false>(A, B, C, m0, n0, N, 2048, As, Bs);
}

// Output projection: out = ctx * Wo^T, fp32 out; XCD-chunked swizzle (nwg=512)
__global__ __launch_bounds__(256, 2)
void gemm_out(const u16* __restrict__ A, const u16* __restrict__ B, float* __restrict__ C) {
  __shared__ u16 As[128 * 32];
  __shared__ u16 Bs[128 * 32];
  const int flat = blockIdx.x + (blockIdx.y << 4);
  const int work = ((flat & 7) << 6) + (flat >> 3);
  const int m0 = (work >> 4) << 7, n0 = (work & 15) << 7;
  gemm_body<true>(A, B, C, m0, n0, 2048, 2048, As, Bs);
}

// ---------- attention: per-64-key-block softmax, block outputs summed ----------
// v3: 512 threads / 8 waves (16 q-rows each) -> 4 waves/SIMD (was 2); XCD-chunked
// block swizzle so each XCD owns 4 heads' K/V (4 MB = one L2). Double-buffered
// K/V staging, single vmcnt(0)+s_barrier per iter, setprio around MFMA.
// Vt layout: [d 2048][b*2048+s] (row stride 4096).
__global__ __launch_bounds__(512, 4)
void attn_kernel(const u16* __restrict__ Q, const u16* __restrict__ Kmat,
                 const u16* __restrict__ Vt, float* __restrict__ attn_out,
                 u16* __restrict__ ctx) {
  __shared__ u16 Ks[2][64 * 128];   // [key][hd], 16B-chunk pos = c ^ (key&15)
  __shared__ u16 Vts[2][128 * 64];  // [dd][key], chunk pos = c ^ (dd&7)
  __shared__ u16 Ps[128 * 64];      // [qrow][key], chunk pos = c ^ (row&7); wave-private rows
  const int tid = threadIdx.x, lane = tid & 63, w = tid >> 6;  // w in 0..7
  // T1 swizzle: flat grid (16,16,2) = 512 blocks; XCD x gets contiguous 64 works
  const int flat = blockIdx.x + (blockIdx.y << 4) + (blockIdx.z << 8);
  const int work = ((flat & 7) << 6) + (flat >> 3);
  const int qt = work & 15, h = (work >> 4) & 15, b = work >> 8;
  const int q0 = qt * 128;
  const int fm = lane & 15, quad = lane >> 4;
  // (1/sqrt(128)) * log2(e): softmax exp((v-mx)/scale) == exp2((v-mx)*c)
  const float c_e2 = 0.088388347648318447f * 1.4426950408889634f;

  // Q fragments in registers: wave w owns q-rows [w*16, w*16+16)
  bf16x8 qf[4];
  {
    const u16* Qg = Q + (size_t)(b * 2048 + q0 + w * 16 + fm) * 2048 + h * 128;
#pragma unroll
    for (int kt = 0; kt < 4; kt++)
      qf[kt] = *(const bf16x8*)(Qg + kt * 32 + quad * 8);
  }
  f32x4 cacc[8] = {};  // ctx accumulator, persists across all 32 k-blocks
  const u16* Kg = Kmat + (size_t)b * 2048 * 2048 + h * 128;
  const u16* Vg = Vt + (size_t)(h * 128) * 4096 + b * 2048;
  const int krl = lane >> 4, kcl = lane & 15;  // K staging: 4 rows x 16 chunks / issue
  const int vrl = lane >> 3, vcl = lane & 7;   // V staging: 8 rows x 8 chunks / issue

#define STAGE(buf, kbb)                                                              \
  for (int i = w; i < 16; i += 8) {                                                  \
    int rk = i * 4 + krl;                                                            \
    int ck = kcl ^ (rk & 15);                                                        \
    gl_lds16(Kg + (size_t)((kbb) * 64 + rk) * 2048 + ck * 8, &Ks[(buf)][i * 512]);   \
    int rv = i * 8 + vrl;                                                            \
    int cv = vcl ^ (rv & 7);                                                         \
    gl_lds16(Vg + (size_t)rv * 4096 + (kbb) * 64 + cv * 8, &Vts[(buf)][i * 512]);    \
  }

  // prologue: stage k-block 0 into buffer 0
  STAGE(0, 0)
  asm volatile("s_waitcnt vmcnt(0)" ::: "memory");
  __builtin_amdgcn_s_barrier();

  for (int kb = 0; kb < 32; kb++) {
    const int cur = kb & 1;
    // issue next tile's async loads first; latency hides under compute below
    if (kb < 31) { STAGE(cur ^ 1, kb + 1) }

    // S = Q K^T  (this wave: 16 q-rows x 64 keys)
    f32x4 sacc[4] = {};
#pragma unroll
    for (int kt = 0; kt < 4; kt++) {
      bf16x8 kf[4];
#pragma unroll
      for (int nt = 0; nt < 4; nt++) {
        int rk = nt * 16 + fm;
        int ck = (kt * 4 + quad) ^ (rk & 15);
        kf[nt] = *(const bf16x8*)&Ks[cur][rk * 128 + ck * 8];
      }
      __builtin_amdgcn_s_setprio(1);
#pragma unroll
      for (int nt = 0; nt < 4; nt++)
        sacc[nt] = __builtin_amdgcn_mfma_f32_16x16x32_bf16(qf[kt], kf[nt], sacc[nt], 0, 0, 0);
      __builtin_amdgcn_s_setprio(0);
    }

    // per-row softmax over this 64-key block; write fp32 probs + bf16 P tile
#pragma unroll
    for (int r = 0; r < 4; r++) {
      float v0 = sacc[0][r], v1 = sacc[1][r], v2 = sacc[2][r], v3 = sacc[3][r];
      float mx = fmaxf(fmaxf(v0, v1), fmaxf(v2, v3));
      mx = fmaxf(mx, __shfl_xor(mx, 1));
      mx = fmaxf(mx, __shfl_xor(mx, 2));
      mx = fmaxf(mx, __shfl_xor(mx, 4));
      mx = fmaxf(mx, __shfl_xor(mx, 8));
      float e0 = exp2f((v0 - mx) * c_e2);
      float e1 = exp2f((v1 - mx) * c_e2);
      float e2 = exp2f((v2 - mx) * c_e2);
      float e3 = exp2f((v3 - mx) * c_e2);
      float s = e0 + e1 + e2 + e3;
      s += __shfl_xor(s, 1);
      s += __shfl_xor(s, 2);
      s += __shfl_xor(s, 4);
      s += __shfl_xor(s, 8);
      float inv = __builtin_amdgcn_rcpf(s);  // s in [1,64]; ~1ulp, well within tol
      float p0 = e0 * inv, p1 = e1 * inv, p2 = e2 * inv, p3 = e3 * inv;
      int row = w * 16 + quad * 4 + r;
      size_t ob = ((size_t)((b * 16 + h) * 2048 + q0 + row)) * 2048 + kb * 64;
      attn_out[ob + fm] = p0;
      attn_out[ob + 16 + fm] = p1;
      attn_out[ob + 32 + fm] = p2;
      attn_out[ob + 48 + fm] = p3;
      int rw7 = row & 7, fh = fm >> 3, fl = fm & 7;
      u16* pp = &Ps[row * 64];
      pp[(((0 + fh) ^ rw7) << 3) + fl] = f2bf(p0);
      pp[(((2 + fh) ^ rw7) << 3) + fl] = f2bf(p1);
      pp[(((4 + fh) ^ rw7) << 3) + fl] = f2bf(p2);
      pp[(((6 + fh) ^ rw7) << 3) + fl] = f2bf(p3);
    }

    // ctx += P * V   (Ps rows are wave-private: no barrier needed)
#pragma unroll
    for (int kt = 0; kt < 2; kt++) {
      bf16x8 pa, vb[8];
      {
        int rp = w * 16 + fm;
        int cp = (kt * 4 + quad) ^ (rp & 7);
        pa = *(const bf16x8*)&Ps[rp * 64 + cp * 8];
      }
#pragma unroll
      for (int nt = 0; nt < 8; nt++) {
        int rv = nt * 16 + fm;
        int cv = (kt * 4 + quad) ^ (rv & 7);
        vb[nt] = *(const bf16x8*)&Vts[cur][rv * 64 + cv * 8];
      }
      __builtin_amdgcn_s_setprio(1);
#pragma unroll
      for (int nt = 0; nt < 8; nt++)
        cacc[nt] = __builtin_amdgcn_mfma_f32_16x16x32_bf16(pa, vb[nt], cacc[nt], 0, 0, 0);
      __builtin_amdgcn_s_setprio(0);
    }

    // prefetch (issued at top of iter) has had the whole compute phase to land
    if (kb < 31) {
      asm volatile("s_waitcnt vmcnt(0)" ::: "memory");
      __builtin_amdgcn_s_barrier();
    }
  }
#undef STAGE

  // ctx [B,S,D] layout (= transpose(0,2,1,3).reshape fused)
#pragma unroll
  for (int nt = 0; nt < 8; nt++)
#pragma unroll
    for (int r = 0; r < 4; r++) {
      int row = q0 + w * 16 + quad * 4 + r;
      int col = h * 128 + nt * 16 + fm;
      ctx[(size_t)(b * 2048 + row) * 2048 + col] = f2bf(cacc[nt][r]);
    }
}

extern "C" void kernel_launch(void* const* d_in, const int* in_sizes, int n_in,
                              void* d_out, int out_size, void* d_ws, size_t ws_size,
                              hipStream_t stream) {
  const float* query = (const float*)d_in[0];
  const float* key   = (const float*)d_in[1];
  const float* value = (const float*)d_in[2];
  const float* Wq = (const float*)d_in[3];
  const float* Wk = (const float*)d_in[4];
  const float* Wv = (const float*)d_in[5];
  const float* Wo = (const float*)d_in[6];
  // d_in[7] = block_size (fixed 64)

  float* out  = (float*)d_out;
  float* attn = out + (size_t)8388608;  // [B,H,S,S] region

  // workspace (bf16, 96 MiB)
  u16* ws  = (u16*)d_ws;
  u16* wqb = ws;
  u16* wkb = wqb + 4194304;
  u16* wvb = wkb + 4194304;
  u16* wob = wvb + 4194304;
  u16* Qb  = wob + 4194304;
  u16* Kb  = Qb + 8388608;
  u16* Vtb = Kb + 8388608;   // [d 2048][b*s 4096] = V^T, written directly by gemm_qkv
  u16* ctx = Vtb + 8388608;
  // bf16 input copies live in the attn-weights region (dead before attn writes it)
  u16* Xq = (u16*)attn;
  u16* Xk = Xq + 8388608;
  u16* Xv = Xk + 8388608;

  cvt_all<<<20480, 256, 0, stream>>>(query, key, value, Wq, Wk, Wv, Wo,
                                     Xq, Xk, Xv, wqb, wkb, wvb, wob);

  gemm_qkv<<<dim3(512, 3, 1), 256, 0, stream>>>(Xq, wqb, Qb, Xk, wkb, Kb, Xv, wvb, Vtb);

  attn_kernel<<<dim3(16, 16, 2), 512, 0, stream>>>(Qb, Kb, Vtb, attn, ctx);

  gemm_out<<<dim3(16, 32, 1), 256, 0, stream>>>(ctx, wob, out);
}